// Round 8
// baseline (720.032 us; speedup 1.0000x reference)
//
#include <hip/hip_runtime.h>
#include <hip/hip_bf16.h>

typedef __attribute__((ext_vector_type(8))) short short8;
typedef __attribute__((ext_vector_type(4))) float f32x4;

#define BQ 8
#define SEQ 4096
#define CH 512
#define NHD 8
#define HD 64
#define K3C 1536
#define MTOK 32768
#define NSPL 8

__device__ __forceinline__ float bfu2f(unsigned int u) {
  u <<= 16;
  float f;
  __builtin_memcpy(&f, &u, 4);
  return f;
}
__device__ __forceinline__ unsigned short f2bfu(float x) {
  __hip_bfloat16 h = __float2bfloat16(x);
  unsigned short u;
  __builtin_memcpy(&u, &h, 2);
  return u;
}

__device__ __forceinline__ void gload_lds16(const void* g, void* l) {
  __builtin_amdgcn_global_load_lds(
      (const __attribute__((address_space(1))) unsigned int*)g,
      (__attribute__((address_space(3))) unsigned int*)l, 16, 0, 0);
}

// ---------------- cast kernels ----------------
__global__ __launch_bounds__(256) void cast_f32_bf16(const float* __restrict__ in,
                                                     unsigned short* __restrict__ out, int n4) {
  int stride = gridDim.x * blockDim.x;
  for (int i = blockIdx.x * blockDim.x + threadIdx.x; i < n4; i += stride) {
    float4 v = reinterpret_cast<const float4*>(in)[i];
    ushort4 o;
    o.x = f2bfu(v.x); o.y = f2bfu(v.y); o.z = f2bfu(v.z); o.w = f2bfu(v.w);
    reinterpret_cast<ushort4*>(out)[i] = o;
  }
}

// in: f32 [R][Cc] row-major -> out: bf16 [Cc][R]
__global__ __launch_bounds__(256) void transpose_cast(const float* __restrict__ in,
                                                      unsigned short* __restrict__ out,
                                                      int R, int Cc) {
  __shared__ float tile[32][33];
  const int tx = threadIdx.x, ty = threadIdx.y;  // 32 x 8
  const int c0 = blockIdx.x * 32, r0 = blockIdx.y * 32;
  #pragma unroll
  for (int dy = 0; dy < 32; dy += 8)
    tile[ty + dy][tx] = in[(size_t)(r0 + ty + dy) * Cc + (c0 + tx)];
  __syncthreads();
  #pragma unroll
  for (int dy = 0; dy < 32; dy += 8)
    out[(size_t)(c0 + ty + dy) * R + (r0 + tx)] = f2bfu(tile[tx][ty + dy]);
}

// ---------------- 256x256 tile, BK=32, dbuf 64KB -> 2 blocks/CU ----------------
// Operand tiles 256x32 packed as physical [128][128B]: phys_row = m&127,
// phys 16B-slot slin = (m>>7)*4 + (k>>3), stored at slot slin ^ (prow&7)
// (round-2-verified zero-conflict geometry).  Staging: global_load_lds linear
// dest; per-lane pre-swizzled source slin = (l&7)^(l>>3).
// One barrier + one vmcnt(0) per K-tile; 2 blocks/CU provide TLP across drains.
// MODE 0: QKV. Q/K blocks (n0<1024): 2-pass LDS-transpose epilogue -> qkT.
//         V blocks: direct vb[bh][n][d] stores.
// MODE 1: proj -> f32 out + bias, row-major.
template <int MODE>
__global__ __launch_bounds__(512, 4) void gemm256(const unsigned short* __restrict__ A,
                                                  const unsigned short* __restrict__ Bt,
                                                  void* __restrict__ out0,
                                                  void* __restrict__ out1,
                                                  const float* __restrict__ bias,
                                                  int M, int Nn, int Kk, int nbx) {
  __shared__ __align__(16) char lds[65536];
  const int nwg = gridDim.x;
  int wg = blockIdx.x;
  wg = (wg & 7) * (nwg >> 3) + (wg >> 3);  // XCD swizzle (nwg % 8 == 0)
  const int bx = wg % nbx, by = wg / nbx;
  const int m0 = by * 256, n0 = bx * 256;

  const int tid = threadIdx.x, wave = tid >> 6, lane = tid & 63;
  const int wr = wave >> 2, wc = wave & 3;
  const int l15 = lane & 15, lg = lane >> 4;
  const int T = Kk >> 5;

  f32x4 acc[2][4][2][2] = {};
  short8 af[4], b0[2], b1[2];

  const int prow_l = (lane >> 3);             // 0..7
  const int slin_l = (lane & 7) ^ (lane >> 3);  // pre-swizzled source slot

  auto stageA = [&](int kt, char* buf) {
    #pragma unroll
    for (int j = 0; j < 2; ++j) {
      const int pb = (wave * 2 + j) * 8;
      const unsigned short* g = A + (size_t)(m0 + ((slin_l >> 2) << 7) + pb + prow_l) * Kk +
                                kt + ((slin_l & 3) << 3);
      gload_lds16(g, buf + pb * 128);
    }
  };
  auto stageB = [&](int kt, char* buf) {
    #pragma unroll
    for (int j = 0; j < 2; ++j) {
      const int pb = (wave * 2 + j) * 8;
      const unsigned short* g = Bt + (size_t)(n0 + ((slin_l >> 2) << 7) + pb + prow_l) * Kk +
                                kt + ((slin_l & 3) << 3);
      gload_lds16(g, buf + 16384 + pb * 128);
    }
  };

  auto dsA = [&](int qa, const char* bufc) {
    #pragma unroll
    for (int fr = 0; fr < 4; ++fr) {
      const int prow = wr * 64 + fr * 16 + l15;
      const int s = ((qa << 2) + lg) ^ (l15 & 7);
      af[fr] = *reinterpret_cast<const short8*>(bufc + prow * 128 + (s << 4));
    }
  };
  auto dsB = [&](int qb, const char* bufc, short8* bset) {
    #pragma unroll
    for (int fc = 0; fc < 2; ++fc) {
      const int prow = wc * 32 + fc * 16 + l15;
      const int s = ((qb << 2) + lg) ^ (l15 & 7);
      bset[fc] = *reinterpret_cast<const short8*>(bufc + 16384 + prow * 128 + (s << 4));
    }
  };
  auto mfma8 = [&](int qa, int qb, const short8* bset) {
    __builtin_amdgcn_s_setprio(1);
    #pragma unroll
    for (int fr = 0; fr < 4; ++fr)
      #pragma unroll
      for (int fc = 0; fc < 2; ++fc)
        acc[qa][fr][qb][fc] = __builtin_amdgcn_mfma_f32_16x16x32_bf16(
            af[fr], bset[fc], acc[qa][fr][qb][fc], 0, 0, 0);
    __builtin_amdgcn_s_setprio(0);
  };

  // prologue: stage K-tile 0 into buf0
  stageA(0, lds);
  stageB(0, lds);
  asm volatile("s_waitcnt vmcnt(0)" ::: "memory");
  __builtin_amdgcn_s_barrier();

  for (int t = 0; t < T; ++t) {
    char* bufc = lds + ((t & 1) << 15);
    char* bufn = lds + (((t + 1) & 1) << 15);
    const int ktn = (t + 1) << 5;
    const bool st = (t < T - 1);

    dsA(0, bufc);
    dsB(0, bufc, b0);
    if (st) { stageA(ktn, bufn); stageB(ktn, bufn); }
    mfma8(0, 0, b0);
    dsB(1, bufc, b1);
    mfma8(0, 1, b1);
    dsA(1, bufc);
    mfma8(1, 1, b1);
    mfma8(1, 0, b0);
    if (st) asm volatile("s_waitcnt vmcnt(0)" ::: "memory");
    __builtin_amdgcn_s_barrier();
  }

  // ---------------- epilogue ----------------
  if (MODE == 1) {
    #pragma unroll
    for (int qa = 0; qa < 2; ++qa)
      #pragma unroll
      for (int fr = 0; fr < 4; ++fr)
        #pragma unroll
        for (int qb = 0; qb < 2; ++qb)
          #pragma unroll
          for (int fc = 0; fc < 2; ++fc) {
            const int row0 = m0 + wr * 64 + qa * 128 + fr * 16 + lg * 4;
            const int col = n0 + wc * 32 + qb * 128 + fc * 16 + l15;
            #pragma unroll
            for (int v = 0; v < 4; ++v)
              reinterpret_cast<float*>(out0)[(size_t)(row0 + v) * Nn + col] =
                  acc[qa][fr][qb][fc][v] + bias[col];
          }
  } else if (n0 < 1024) {
    // Q/K block: two 64-KB LDS-transpose passes (qb halves) -> coalesced qkT stores.
    #pragma unroll
    for (int qb = 0; qb < 2; ++qb) {
      __builtin_amdgcn_s_barrier();
      #pragma unroll
      for (int qa = 0; qa < 2; ++qa)
        #pragma unroll
        for (int fr = 0; fr < 4; ++fr)
          #pragma unroll
          for (int fc = 0; fc < 2; ++fc) {
            const int nl = wr * 64 + qa * 128 + fr * 16 + lg * 4;  // token-local
            const int cl = wc * 32 + fc * 16 + l15;                // col within half
            ushort4 o;
            o.x = f2bfu(acc[qa][fr][qb][fc][0]);
            o.y = f2bfu(acc[qa][fr][qb][fc][1]);
            o.z = f2bfu(acc[qa][fr][qb][fc][2]);
            o.w = f2bfu(acc[qa][fr][qb][fc][3]);
            const int byte = cl * 512 + ((nl * 2) ^ ((cl & 7) << 4));
            *reinterpret_cast<ushort4*>(lds + byte) = o;
          }
      __builtin_amdgcn_s_barrier();
      #pragma unroll
      for (int it = 0; it < 8; ++it) {
        const int cl = it * 16 + (tid >> 5);
        const int ns = (tid & 31) * 8;
        const int byte = cl * 512 + ((ns * 2) ^ ((cl & 7) << 4));
        short8 val = *reinterpret_cast<const short8*>(lds + byte);
        const int gcol = n0 + qb * 128 + cl;
        const int sel = gcol >> 9, rem = gcol & 511;
        const int bh = (m0 >> 12) * 8 + (rem >> 6), cc = rem & 63;
        *reinterpret_cast<short8*>(&reinterpret_cast<unsigned short*>(out0)[
            ((size_t)sel * 4096 + bh * 64 + cc) * 4096 + (m0 & 4095) + ns]) = val;
      }
    }
  } else {
    // V block: direct vb[bh][n][d] stores
    #pragma unroll
    for (int qa = 0; qa < 2; ++qa)
      #pragma unroll
      for (int fr = 0; fr < 4; ++fr)
        #pragma unroll
        for (int qb = 0; qb < 2; ++qb)
          #pragma unroll
          for (int fc = 0; fc < 2; ++fc) {
            const int row0 = m0 + wr * 64 + qa * 128 + fr * 16 + lg * 4;
            const int col = n0 + wc * 32 + qb * 128 + fc * 16 + l15;
            const int rem = col & 511, hh = rem >> 6, cc = rem & 63;
            const int bb = row0 >> 12, nseq = row0 & 4095;
            const int bh = bb * 8 + hh;
            #pragma unroll
            for (int v = 0; v < 4; ++v)
              reinterpret_cast<unsigned short*>(out1)[
                  ((size_t)bh * 4096 + nseq + v) * 64 + cc] =
                  f2bfu(acc[qa][fr][qb][fc][v]);
          }
  }
}

// ---------------- attn QK^T via MFMA: rawp[s][bh][c][d] partials + norms ----------------
// qkT: [sel][bh][c][n] bf16 (sel 0=Q,1=K), rows of 4096.
__global__ __launch_bounds__(256) void attn_qk(const unsigned short* __restrict__ qkT,
                                               float* __restrict__ rawp,
                                               float* __restrict__ normp) {
  const int bh = blockIdx.x, s = blockIdx.y;
  const int tid = threadIdx.x, w = tid >> 6, lane = tid & 63;
  const int l15 = lane & 15, lg = lane >> 4;
  const int nbase = s * 512 + w * 128;
  const unsigned short* qrow = qkT + (size_t)(bh * 64) * 4096;
  const unsigned short* krow = qkT + (size_t)(4096 + bh * 64) * 4096;

  __shared__ float red[4][64][64];
  __shared__ float nrm[4][2][64];

  f32x4 acc[4][4] = {};
  float sq[4] = {0.f, 0.f, 0.f, 0.f}, sk[4] = {0.f, 0.f, 0.f, 0.f};

  #pragma unroll
  for (int kc = 0; kc < 2; ++kc) {
    short8 aq[4][2], bk[4][2];
    #pragma unroll
    for (int fr = 0; fr < 4; ++fr)
      #pragma unroll
      for (int ks = 0; ks < 2; ++ks) {
        const size_t off = (size_t)(fr * 16 + l15) * 4096 + nbase + (kc * 2 + ks) * 32 + lg * 8;
        aq[fr][ks] = *reinterpret_cast<const short8*>(&qrow[off]);
        bk[fr][ks] = *reinterpret_cast<const short8*>(&krow[off]);
      }
    #pragma unroll
    for (int ks = 0; ks < 2; ++ks)
      #pragma unroll
      for (int fr = 0; fr < 4; ++fr)
        #pragma unroll
        for (int fc = 0; fc < 4; ++fc)
          acc[fr][fc] = __builtin_amdgcn_mfma_f32_16x16x32_bf16(
              aq[fr][ks], bk[fc][ks], acc[fr][fc], 0, 0, 0);
    #pragma unroll
    for (int fr = 0; fr < 4; ++fr)
      #pragma unroll
      for (int ks = 0; ks < 2; ++ks)
        #pragma unroll
        for (int j = 0; j < 8; ++j) {
          const float fq = bfu2f((unsigned short)aq[fr][ks][j]);
          const float fk = bfu2f((unsigned short)bk[fr][ks][j]);
          sq[fr] = fmaf(fq, fq, sq[fr]);
          sk[fr] = fmaf(fk, fk, sk[fr]);
        }
  }

  #pragma unroll
  for (int fr = 0; fr < 4; ++fr) {
    sq[fr] += __shfl_xor(sq[fr], 16); sq[fr] += __shfl_xor(sq[fr], 32);
    sk[fr] += __shfl_xor(sk[fr], 16); sk[fr] += __shfl_xor(sk[fr], 32);
  }
  if (lane < 16) {
    #pragma unroll
    for (int fr = 0; fr < 4; ++fr) {
      nrm[w][0][fr * 16 + lane] = sq[fr];
      nrm[w][1][fr * 16 + lane] = sk[fr];
    }
  }
  #pragma unroll
  for (int fr = 0; fr < 4; ++fr)
    #pragma unroll
    for (int fc = 0; fc < 4; ++fc)
      #pragma unroll
      for (int v = 0; v < 4; ++v)
        red[w][fr * 16 + lg * 4 + v][fc * 16 + l15] = acc[fr][fc][v];
  __syncthreads();

  const float* rf = &red[0][0][0];
  float* rp = rawp + ((size_t)s * 64 + bh) * 4096;
  for (int i = tid; i < 4096; i += 256)
    rp[i] = rf[i] + rf[4096 + i] + rf[8192 + i] + rf[12288 + i];
  const float* nf = &nrm[0][0][0];
  if (tid < 128) {
    float* np = normp + ((size_t)s * 64 + bh) * 128;
    np[tid] = nf[tid] + nf[128 + tid] + nf[256 + tid] + nf[384 + tid];
  }
}

// ---------------- finalize: reduce partials, normalize, softmax ----------------
__global__ __launch_bounds__(64) void attn_finalize(const float* __restrict__ rawp,
                                                    const float* __restrict__ normp,
                                                    const float* __restrict__ temperature,
                                                    unsigned short* __restrict__ attnP) {
  const int bh = blockIdx.x, c8 = blockIdx.y, h = bh & 7;
  const int d = threadIdx.x;
  float nq = 0.f, nk = 0.f;
  for (int s = 0; s < NSPL; ++s) {
    nq += normp[((size_t)s * 64 + bh) * 128 + d];
    nk += normp[((size_t)s * 64 + bh) * 128 + 64 + d];
  }
  nq = fmaxf(sqrtf(nq), 1e-12f);
  nk = fmaxf(sqrtf(nk), 1e-12f);
  const float t = temperature[h];
  for (int i = 0; i < 8; ++i) {
    const int c = c8 * 8 + i;
    float r = 0.f;
    for (int s = 0; s < NSPL; ++s)
      r += rawp[((size_t)s * 64 + bh) * 4096 + c * 64 + d];
    const float nqc = __shfl(nq, c);
    float v = r * t / (nqc * nk);
    float m = v;
    #pragma unroll
    for (int off = 32; off > 0; off >>= 1) m = fmaxf(m, __shfl_xor(m, off));
    float e = __expf(v - m);
    float ssum = e;
    #pragma unroll
    for (int off = 32; off > 0; off >>= 1) ssum += __shfl_xor(ssum, off);
    attnP[(size_t)bh * 4096 + c * 64 + d] = f2bfu(e / ssum);
  }
}

// ---------------- PV via MFMA: y[b*4096+n][h*64+c] = sum_d P[c,d] * vb[bh][n][d] --------
__global__ __launch_bounds__(256) void pv_mfma(const unsigned short* __restrict__ attnP,
                                               const unsigned short* __restrict__ vb,
                                               unsigned short* __restrict__ y) {
  const int nc = blockIdx.x, bh = blockIdx.y;
  const int b = bh >> 3, h = bh & 7;
  const int tid = threadIdx.x, w = tid >> 6, lane = tid & 63;
  const int l15 = lane & 15, lg = lane >> 4;
  const int n0 = nc * 256 + w * 64;

  short8 ap[4][2], bv[4][2];
  #pragma unroll
  for (int fr = 0; fr < 4; ++fr)
    #pragma unroll
    for (int ks = 0; ks < 2; ++ks)
      ap[fr][ks] = *reinterpret_cast<const short8*>(
          &attnP[(size_t)bh * 4096 + (fr * 16 + l15) * 64 + ks * 32 + lg * 8]);
  #pragma unroll
  for (int fc = 0; fc < 4; ++fc)
    #pragma unroll
    for (int ks = 0; ks < 2; ++ks)
      bv[fc][ks] = *reinterpret_cast<const short8*>(
          &vb[((size_t)bh * 4096 + n0 + fc * 16 + l15) * 64 + ks * 32 + lg * 8]);

  f32x4 acc[4][4] = {};
  #pragma unroll
  for (int ks = 0; ks < 2; ++ks)
    #pragma unroll
    for (int fr = 0; fr < 4; ++fr)
      #pragma unroll
      for (int fc = 0; fc < 4; ++fc)
        acc[fr][fc] = __builtin_amdgcn_mfma_f32_16x16x32_bf16(
            ap[fr][ks], bv[fc][ks], acc[fr][fc], 0, 0, 0);

  #pragma unroll
  for (int fr = 0; fr < 4; ++fr)
    #pragma unroll
    for (int fc = 0; fc < 4; ++fc) {
      const int n = n0 + fc * 16 + l15;
      const int c0 = fr * 16 + lg * 4;
      ushort4 o;
      o.x = f2bfu(acc[fr][fc][0]); o.y = f2bfu(acc[fr][fc][1]);
      o.z = f2bfu(acc[fr][fc][2]); o.w = f2bfu(acc[fr][fc][3]);
      *reinterpret_cast<ushort4*>(
          &y[((size_t)b * 4096 + n) * 512 + h * 64 + c0]) = o;
    }
}

extern "C" void kernel_launch(void* const* d_in, const int* in_sizes, int n_in,
                              void* d_out, int out_size, void* d_ws, size_t ws_size,
                              hipStream_t stream) {
  const float* x = (const float*)d_in[0];
  const float* Wqkv = (const float*)d_in[2];
  const float* temp = (const float*)d_in[3];
  const float* Wproj = (const float*)d_in[4];
  const float* bproj = (const float*)d_in[5];
  float* out = (float*)d_out;

  char* w = (char*)d_ws;
  unsigned short* xb = (unsigned short*)w;    w += (size_t)MTOK * CH * 2;
  unsigned short* wqT = (unsigned short*)w;   w += (size_t)K3C * CH * 2;
  unsigned short* wpT = (unsigned short*)w;   w += (size_t)CH * CH * 2;
  unsigned short* qkT = (unsigned short*)w;   w += (size_t)2 * 64 * 64 * 4096 * 2;
  unsigned short* vb = (unsigned short*)w;    w += (size_t)64 * 4096 * 64 * 2;
  unsigned short* yb = (unsigned short*)w;    w += (size_t)MTOK * CH * 2;
  float* rawp = (float*)w;                    w += (size_t)NSPL * 64 * 4096 * 4;
  float* normp = (float*)w;                   w += (size_t)NSPL * 64 * 128 * 4;
  unsigned short* attnP = (unsigned short*)w; w += (size_t)64 * 4096 * 2;

  cast_f32_bf16<<<2048, 256, 0, stream>>>(x, xb, MTOK * CH / 4);
  transpose_cast<<<dim3(K3C / 32, CH / 32), dim3(32, 8), 0, stream>>>(Wqkv, wqT, CH, K3C);
  transpose_cast<<<dim3(CH / 32, CH / 32), dim3(32, 8), 0, stream>>>(Wproj, wpT, CH, CH);
  gemm256<0><<<768, 512, 0, stream>>>(xb, wqT, qkT, vb, nullptr, MTOK, K3C, CH, 6);
  attn_qk<<<dim3(64, 8), 256, 0, stream>>>(qkT, rawp, normp);
  attn_finalize<<<dim3(64, 8), 64, 0, stream>>>(rawp, normp, temp, attnP);
  pv_mfma<<<dim3(16, 64), 256, 0, stream>>>(attnP, vb, yb);
  gemm256<1><<<256, 512, 0, stream>>>(yb, wpT, out, nullptr, bproj, MTOK, CH, CH, 2);
}

// Round 10
// 161.987 us; speedup vs baseline: 4.4450x; 4.4450x over previous
//
#include <hip/hip_runtime.h>
#include <hip/hip_bf16.h>

typedef __attribute__((ext_vector_type(8))) short short8;
typedef __attribute__((ext_vector_type(4))) float f32x4;

#define BQ 8
#define SEQ 4096
#define CH 512
#define NHD 8
#define HD 64
#define K3C 1536
#define MTOK 32768
#define NSPL 8

__device__ __forceinline__ float bfu2f(unsigned int u) {
  u <<= 16;
  float f;
  __builtin_memcpy(&f, &u, 4);
  return f;
}
__device__ __forceinline__ unsigned short f2bfu(float x) {
  __hip_bfloat16 h = __float2bfloat16(x);
  unsigned short u;
  __builtin_memcpy(&u, &h, 2);
  return u;
}

__device__ __forceinline__ void gload_lds16(const void* g, void* l) {
  __builtin_amdgcn_global_load_lds(
      (const __attribute__((address_space(1))) unsigned int*)g,
      (__attribute__((address_space(3))) unsigned int*)l, 16, 0, 0);
}

// ---------------- cast kernels ----------------
__global__ __launch_bounds__(256) void cast_f32_bf16(const float* __restrict__ in,
                                                     unsigned short* __restrict__ out, int n4) {
  int stride = gridDim.x * blockDim.x;
  for (int i = blockIdx.x * blockDim.x + threadIdx.x; i < n4; i += stride) {
    float4 v = reinterpret_cast<const float4*>(in)[i];
    ushort4 o;
    o.x = f2bfu(v.x); o.y = f2bfu(v.y); o.z = f2bfu(v.z); o.w = f2bfu(v.w);
    reinterpret_cast<ushort4*>(out)[i] = o;
  }
}

// in: f32 [R][Cc] row-major -> out: bf16 [Cc][R]
__global__ __launch_bounds__(256) void transpose_cast(const float* __restrict__ in,
                                                      unsigned short* __restrict__ out,
                                                      int R, int Cc) {
  __shared__ float tile[32][33];
  const int tx = threadIdx.x, ty = threadIdx.y;  // 32 x 8
  const int c0 = blockIdx.x * 32, r0 = blockIdx.y * 32;
  #pragma unroll
  for (int dy = 0; dy < 32; dy += 8)
    tile[ty + dy][tx] = in[(size_t)(r0 + ty + dy) * Cc + (c0 + tx)];
  __syncthreads();
  #pragma unroll
  for (int dy = 0; dy < 32; dy += 8)
    out[(size_t)(c0 + ty + dy) * R + (r0 + tx)] = f2bfu(tile[tx][ty + dy]);
}

// ------- 256x128 tile, 8 waves x (64x64), BK=32, dbuf 48KB, 2 blocks/CU -------
// Per-wave acc = 64 VGPR (64x64 out), +frags ~32 -> fits 128-VGPR cap at 4 waves/EU.
// A tile 256x32 packed [128 prow][8 slots of 16B]: prow=m&127, slin=(m>>7)*4+(k>>3),
// stored slot s = slin ^ (prow&7)  (round-2-verified zero-conflict family).
// B tile 128x32 packed [64 prow][8 slots]: prow=n&63, slin=(n>>6)*4+(k>>3).
// Staging: slot L = tid (= wave*64+lane); LDS dest MUST carry the wave offset
// (global_load_lds writes wave-uniform-base + lane*16) -> dest = buf + wave*1024.
// Global source (m,k)/(n,k) recovered from slin = (L&7) ^ ((L>>3)&7).
// One barrier + one vmcnt(0) per K-tile; 2 blocks/CU TLP covers the drain.
// MODE 0: QKV. Q/K blocks (n0<1024): 2-pass LDS-transpose epilogue -> qkT.
//         V blocks: direct vb[bh][n][d] stores.
// MODE 1: proj -> f32 out + bias, row-major.
template <int MODE>
__global__ __launch_bounds__(512, 4) void gemm256(const unsigned short* __restrict__ A,
                                                  const unsigned short* __restrict__ Bt,
                                                  void* __restrict__ out0,
                                                  void* __restrict__ out1,
                                                  const float* __restrict__ bias,
                                                  int M, int Nn, int Kk, int nbx) {
  __shared__ __align__(16) char lds[49152];
  const int nwg = gridDim.x;
  int wg = blockIdx.x;
  wg = (wg & 7) * (nwg >> 3) + (wg >> 3);  // XCD swizzle (nwg % 8 == 0)
  const int bx = wg % nbx, by = wg / nbx;
  const int m0 = by * 256, n0 = bx * 128;

  const int tid = threadIdx.x, wave = tid >> 6, lane = tid & 63;
  const int wr = wave >> 1, wc = wave & 1;
  const int l15 = lane & 15, lg = lane >> 4;
  const int T = Kk >> 5;

  f32x4 acc[4][4] = {};  // 64 VGPRs: wave tile 64 tokens x 64 cols
  short8 af[4], bf[4];

  // staging thread->slot precompute (slot L = tid)
  const int prowA = tid >> 3, sA = tid & 7;
  const int slinA = sA ^ (prowA & 7);
  const int mA = ((slinA >> 2) << 7) + prowA, kA = (slinA & 3) << 3;
  const int prow2 = prowA + 64;                 // second A half: L2 = tid + 512
  const int slin2 = sA ^ (prow2 & 7);           // prow2&7 == prowA&7
  const int m2 = ((slin2 >> 2) << 7) + prow2, k2 = (slin2 & 3) << 3;
  const int prowB = tid >> 3, sB = tid & 7;
  const int slinB = sB ^ (prowB & 7);
  const int nB = ((slinB >> 2) << 6) + prowB, kB = (slinB & 3) << 3;
  const int woff = wave * 1024;                 // per-wave LDS dest offset

  auto stageA = [&](int kt, char* buf) {
    gload_lds16(A + (size_t)(m0 + mA) * Kk + kt + kA, buf + woff);
    gload_lds16(A + (size_t)(m0 + m2) * Kk + kt + k2, buf + 8192 + woff);
  };
  auto stageB = [&](int kt, char* buf) {
    gload_lds16(Bt + (size_t)(n0 + nB) * Kk + kt + kB, buf + 16384 + woff);
  };

  auto dsA = [&](const char* bufc) {
    #pragma unroll
    for (int fr = 0; fr < 4; ++fr) {
      const int m = wr * 64 + fr * 16 + l15;
      const int prow = m & 127;
      const int s = ((m >> 7) * 4 + lg) ^ (l15 & 7);
      af[fr] = *reinterpret_cast<const short8*>(bufc + prow * 128 + (s << 4));
    }
  };
  auto dsB = [&](const char* bufc) {
    #pragma unroll
    for (int fc = 0; fc < 4; ++fc) {
      const int prow = fc * 16 + l15;   // n&63
      const int s = (wc * 4 + lg) ^ (l15 & 7);
      bf[fc] = *reinterpret_cast<const short8*>(bufc + 16384 + prow * 128 + (s << 4));
    }
  };

  // prologue
  stageA(0, lds);
  stageB(0, lds);
  asm volatile("s_waitcnt vmcnt(0)" ::: "memory");
  __builtin_amdgcn_s_barrier();

  for (int t = 0; t < T; ++t) {
    char* bufc = lds + (t & 1) * 24576;
    char* bufn = lds + ((t + 1) & 1) * 24576;
    const int ktn = (t + 1) << 5;
    const bool st = (t < T - 1);

    dsA(bufc);
    dsB(bufc);
    if (st) { stageA(ktn, bufn); stageB(ktn, bufn); }
    __builtin_amdgcn_s_setprio(1);
    #pragma unroll
    for (int fr = 0; fr < 4; ++fr)
      #pragma unroll
      for (int fc = 0; fc < 4; ++fc)
        acc[fr][fc] = __builtin_amdgcn_mfma_f32_16x16x32_bf16(
            af[fr], bf[fc], acc[fr][fc], 0, 0, 0);
    __builtin_amdgcn_s_setprio(0);
    if (st) asm volatile("s_waitcnt vmcnt(0)" ::: "memory");
    __builtin_amdgcn_s_barrier();
  }

  // ---------------- epilogue ----------------
  if (MODE == 1) {
    #pragma unroll
    for (int fr = 0; fr < 4; ++fr)
      #pragma unroll
      for (int fc = 0; fc < 4; ++fc) {
        const int row0 = m0 + wr * 64 + fr * 16 + lg * 4;
        const int col = n0 + wc * 64 + fc * 16 + l15;
        #pragma unroll
        for (int v = 0; v < 4; ++v)
          reinterpret_cast<float*>(out0)[(size_t)(row0 + v) * Nn + col] =
              acc[fr][fc][v] + bias[col];
      }
  } else if (n0 < 1024) {
    // Q/K: two 32-KB LDS-transpose passes (wc halves) -> coalesced qkT stores.
    #pragma unroll
    for (int p = 0; p < 2; ++p) {
      __builtin_amdgcn_s_barrier();
      if (wc == p) {
        #pragma unroll
        for (int fr = 0; fr < 4; ++fr)
          #pragma unroll
          for (int fc = 0; fc < 4; ++fc) {
            const int tok = wr * 64 + fr * 16 + lg * 4;  // token-local, %4==0
            const int cl = fc * 16 + l15;                // col within 64-half
            ushort4 o;
            o.x = f2bfu(acc[fr][fc][0]);
            o.y = f2bfu(acc[fr][fc][1]);
            o.z = f2bfu(acc[fr][fc][2]);
            o.w = f2bfu(acc[fr][fc][3]);
            const int byte = cl * 512 + ((tok * 2) ^ ((cl & 7) << 4));
            *reinterpret_cast<ushort4*>(lds + byte) = o;
          }
      }
      __builtin_amdgcn_s_barrier();
      #pragma unroll
      for (int it = 0; it < 4; ++it) {
        const int cl = it * 16 + (tid >> 5);
        const int ns = (tid & 31) * 8;
        const int byte = cl * 512 + ((ns * 2) ^ ((cl & 7) << 4));
        short8 val = *reinterpret_cast<const short8*>(lds + byte);
        const int gcol = n0 + p * 64 + cl;
        const int sel = gcol >> 9, rem = gcol & 511;
        const int bh = (m0 >> 12) * 8 + (rem >> 6), cc = rem & 63;
        *reinterpret_cast<short8*>(&reinterpret_cast<unsigned short*>(out0)[
            ((size_t)sel * 4096 + bh * 64 + cc) * 4096 + (m0 & 4095) + ns]) = val;
      }
    }
  } else {
    // V block: direct vb[bh][n][d] stores
    #pragma unroll
    for (int fr = 0; fr < 4; ++fr)
      #pragma unroll
      for (int fc = 0; fc < 4; ++fc) {
        const int row0 = m0 + wr * 64 + fr * 16 + lg * 4;
        const int col = n0 + wc * 64 + fc * 16 + l15;
        const int rem = col & 511, hh = rem >> 6, cc = rem & 63;
        const int bb = row0 >> 12, nseq = row0 & 4095;
        const int bh = bb * 8 + hh;
        #pragma unroll
        for (int v = 0; v < 4; ++v)
          reinterpret_cast<unsigned short*>(out1)[
              ((size_t)bh * 4096 + nseq + v) * 64 + cc] =
              f2bfu(acc[fr][fc][v]);
      }
  }
}

// ---------------- attn QK^T via MFMA: rawp[s][bh][c][d] partials + norms ----------------
// qkT: [sel][bh][c][n] bf16 (sel 0=Q,1=K), rows of 4096.
__global__ __launch_bounds__(256) void attn_qk(const unsigned short* __restrict__ qkT,
                                               float* __restrict__ rawp,
                                               float* __restrict__ normp) {
  const int bh = blockIdx.x, s = blockIdx.y;
  const int tid = threadIdx.x, w = tid >> 6, lane = tid & 63;
  const int l15 = lane & 15, lg = lane >> 4;
  const int nbase = s * 512 + w * 128;
  const unsigned short* qrow = qkT + (size_t)(bh * 64) * 4096;
  const unsigned short* krow = qkT + (size_t)(4096 + bh * 64) * 4096;

  __shared__ float red[4][64][64];
  __shared__ float nrm[4][2][64];

  f32x4 acc[4][4] = {};
  float sq[4] = {0.f, 0.f, 0.f, 0.f}, sk[4] = {0.f, 0.f, 0.f, 0.f};

  #pragma unroll
  for (int kc = 0; kc < 2; ++kc) {
    short8 aq[4][2], bk[4][2];
    #pragma unroll
    for (int fr = 0; fr < 4; ++fr)
      #pragma unroll
      for (int ks = 0; ks < 2; ++ks) {
        const size_t off = (size_t)(fr * 16 + l15) * 4096 + nbase + (kc * 2 + ks) * 32 + lg * 8;
        aq[fr][ks] = *reinterpret_cast<const short8*>(&qrow[off]);
        bk[fr][ks] = *reinterpret_cast<const short8*>(&krow[off]);
      }
    #pragma unroll
    for (int ks = 0; ks < 2; ++ks)
      #pragma unroll
      for (int fr = 0; fr < 4; ++fr)
        #pragma unroll
        for (int fc = 0; fc < 4; ++fc)
          acc[fr][fc] = __builtin_amdgcn_mfma_f32_16x16x32_bf16(
              aq[fr][ks], bk[fc][ks], acc[fr][fc], 0, 0, 0);
    #pragma unroll
    for (int fr = 0; fr < 4; ++fr)
      #pragma unroll
      for (int ks = 0; ks < 2; ++ks)
        #pragma unroll
        for (int j = 0; j < 8; ++j) {
          const float fq = bfu2f((unsigned short)aq[fr][ks][j]);
          const float fk = bfu2f((unsigned short)bk[fr][ks][j]);
          sq[fr] = fmaf(fq, fq, sq[fr]);
          sk[fr] = fmaf(fk, fk, sk[fr]);
        }
  }

  #pragma unroll
  for (int fr = 0; fr < 4; ++fr) {
    sq[fr] += __shfl_xor(sq[fr], 16); sq[fr] += __shfl_xor(sq[fr], 32);
    sk[fr] += __shfl_xor(sk[fr], 16); sk[fr] += __shfl_xor(sk[fr], 32);
  }
  if (lane < 16) {
    #pragma unroll
    for (int fr = 0; fr < 4; ++fr) {
      nrm[w][0][fr * 16 + lane] = sq[fr];
      nrm[w][1][fr * 16 + lane] = sk[fr];
    }
  }
  #pragma unroll
  for (int fr = 0; fr < 4; ++fr)
    #pragma unroll
    for (int fc = 0; fc < 4; ++fc)
      #pragma unroll
      for (int v = 0; v < 4; ++v)
        red[w][fr * 16 + lg * 4 + v][fc * 16 + l15] = acc[fr][fc][v];
  __syncthreads();

  const float* rf = &red[0][0][0];
  float* rp = rawp + ((size_t)s * 64 + bh) * 4096;
  for (int i = tid; i < 4096; i += 256)
    rp[i] = rf[i] + rf[4096 + i] + rf[8192 + i] + rf[12288 + i];
  const float* nf = &nrm[0][0][0];
  if (tid < 128) {
    float* np = normp + ((size_t)s * 64 + bh) * 128;
    np[tid] = nf[tid] + nf[128 + tid] + nf[256 + tid] + nf[384 + tid];
  }
}

// ---------------- finalize: reduce partials, normalize, softmax ----------------
__global__ __launch_bounds__(64) void attn_finalize(const float* __restrict__ rawp,
                                                    const float* __restrict__ normp,
                                                    const float* __restrict__ temperature,
                                                    unsigned short* __restrict__ attnP) {
  const int bh = blockIdx.x, c8 = blockIdx.y, h = bh & 7;
  const int d = threadIdx.x;
  float nq = 0.f, nk = 0.f;
  for (int s = 0; s < NSPL; ++s) {
    nq += normp[((size_t)s * 64 + bh) * 128 + d];
    nk += normp[((size_t)s * 64 + bh) * 128 + 64 + d];
  }
  nq = fmaxf(sqrtf(nq), 1e-12f);
  nk = fmaxf(sqrtf(nk), 1e-12f);
  const float t = temperature[h];
  for (int i = 0; i < 8; ++i) {
    const int c = c8 * 8 + i;
    float r = 0.f;
    for (int s = 0; s < NSPL; ++s)
      r += rawp[((size_t)s * 64 + bh) * 4096 + c * 64 + d];
    const float nqc = __shfl(nq, c);
    float v = r * t / (nqc * nk);
    float m = v;
    #pragma unroll
    for (int off = 32; off > 0; off >>= 1) m = fmaxf(m, __shfl_xor(m, off));
    float e = __expf(v - m);
    float ssum = e;
    #pragma unroll
    for (int off = 32; off > 0; off >>= 1) ssum += __shfl_xor(ssum, off);
    attnP[(size_t)bh * 4096 + c * 64 + d] = f2bfu(e / ssum);
  }
}

// ---------------- PV via MFMA: y[b*4096+n][h*64+c] = sum_d P[c,d] * vb[bh][n][d] --------
__global__ __launch_bounds__(256) void pv_mfma(const unsigned short* __restrict__ attnP,
                                               const unsigned short* __restrict__ vb,
                                               unsigned short* __restrict__ y) {
  const int nc = blockIdx.x, bh = blockIdx.y;
  const int b = bh >> 3, h = bh & 7;
  const int tid = threadIdx.x, w = tid >> 6, lane = tid & 63;
  const int l15 = lane & 15, lg = lane >> 4;
  const int n0 = nc * 256 + w * 64;

  short8 ap[4][2], bv[4][2];
  #pragma unroll
  for (int fr = 0; fr < 4; ++fr)
    #pragma unroll
    for (int ks = 0; ks < 2; ++ks)
      ap[fr][ks] = *reinterpret_cast<const short8*>(
          &attnP[(size_t)bh * 4096 + (fr * 16 + l15) * 64 + ks * 32 + lg * 8]);
  #pragma unroll
  for (int fc = 0; fc < 4; ++fc)
    #pragma unroll
    for (int ks = 0; ks < 2; ++ks)
      bv[fc][ks] = *reinterpret_cast<const short8*>(
          &vb[((size_t)bh * 4096 + n0 + fc * 16 + l15) * 64 + ks * 32 + lg * 8]);

  f32x4 acc[4][4] = {};
  #pragma unroll
  for (int ks = 0; ks < 2; ++ks)
    #pragma unroll
    for (int fr = 0; fr < 4; ++fr)
      #pragma unroll
      for (int fc = 0; fc < 4; ++fc)
        acc[fr][fc] = __builtin_amdgcn_mfma_f32_16x16x32_bf16(
            ap[fr][ks], bv[fc][ks], acc[fr][fc], 0, 0, 0);

  #pragma unroll
  for (int fr = 0; fr < 4; ++fr)
    #pragma unroll
    for (int fc = 0; fc < 4; ++fc) {
      const int n = n0 + fc * 16 + l15;
      const int c0 = fr * 16 + lg * 4;
      ushort4 o;
      o.x = f2bfu(acc[fr][fc][0]); o.y = f2bfu(acc[fr][fc][1]);
      o.z = f2bfu(acc[fr][fc][2]); o.w = f2bfu(acc[fr][fc][3]);
      *reinterpret_cast<ushort4*>(
          &y[((size_t)b * 4096 + n) * 512 + h * 64 + c0]) = o;
    }
}

extern "C" void kernel_launch(void* const* d_in, const int* in_sizes, int n_in,
                              void* d_out, int out_size, void* d_ws, size_t ws_size,
                              hipStream_t stream) {
  const float* x = (const float*)d_in[0];
  const float* Wqkv = (const float*)d_in[2];
  const float* temp = (const float*)d_in[3];
  const float* Wproj = (const float*)d_in[4];
  const float* bproj = (const float*)d_in[5];
  float* out = (float*)d_out;

  char* w = (char*)d_ws;
  unsigned short* xb = (unsigned short*)w;    w += (size_t)MTOK * CH * 2;
  unsigned short* wqT = (unsigned short*)w;   w += (size_t)K3C * CH * 2;
  unsigned short* wpT = (unsigned short*)w;   w += (size_t)CH * CH * 2;
  unsigned short* qkT = (unsigned short*)w;   w += (size_t)2 * 64 * 64 * 4096 * 2;
  unsigned short* vb = (unsigned short*)w;    w += (size_t)64 * 4096 * 64 * 2;
  unsigned short* yb = (unsigned short*)w;    w += (size_t)MTOK * CH * 2;
  float* rawp = (float*)w;                    w += (size_t)NSPL * 64 * 4096 * 4;
  float* normp = (float*)w;                   w += (size_t)NSPL * 64 * 128 * 4;
  unsigned short* attnP = (unsigned short*)w; w += (size_t)64 * 4096 * 2;

  cast_f32_bf16<<<2048, 256, 0, stream>>>(x, xb, MTOK * CH / 4);
  transpose_cast<<<dim3(K3C / 32, CH / 32), dim3(32, 8), 0, stream>>>(Wqkv, wqT, CH, K3C);
  transpose_cast<<<dim3(CH / 32, CH / 32), dim3(32, 8), 0, stream>>>(Wproj, wpT, CH, CH);
  gemm256<0><<<1536, 512, 0, stream>>>(xb, wqT, qkT, vb, nullptr, MTOK, K3C, CH, 12);
  attn_qk<<<dim3(64, 8), 256, 0, stream>>>(qkT, rawp, normp);
  attn_finalize<<<dim3(64, 8), 64, 0, stream>>>(rawp, normp, temp, attnP);
  pv_mfma<<<dim3(16, 64), 256, 0, stream>>>(attnP, vb, yb);
  gemm256<1><<<512, 512, 0, stream>>>(yb, wpT, out, nullptr, bproj, MTOK, CH, CH, 4);
}

// Round 11
// 158.117 us; speedup vs baseline: 4.5538x; 1.0245x over previous
//
#include <hip/hip_runtime.h>
#include <hip/hip_bf16.h>

typedef __attribute__((ext_vector_type(8))) short short8;
typedef __attribute__((ext_vector_type(4))) float f32x4;

#define BQ 8
#define SEQ 4096
#define CH 512
#define NHD 8
#define HD 64
#define K3C 1536
#define MTOK 32768
#define NSPL 8

__device__ __forceinline__ float bfu2f(unsigned int u) {
  u <<= 16;
  float f;
  __builtin_memcpy(&f, &u, 4);
  return f;
}
__device__ __forceinline__ unsigned short f2bfu(float x) {
  __hip_bfloat16 h = __float2bfloat16(x);
  unsigned short u;
  __builtin_memcpy(&u, &h, 2);
  return u;
}

__device__ __forceinline__ void gload_lds16(const void* g, void* l) {
  __builtin_amdgcn_global_load_lds(
      (const __attribute__((address_space(1))) unsigned int*)g,
      (__attribute__((address_space(3))) unsigned int*)l, 16, 0, 0);
}

// ---------------- cast kernels ----------------
__global__ __launch_bounds__(256) void cast_f32_bf16(const float* __restrict__ in,
                                                     unsigned short* __restrict__ out, int n4) {
  int stride = gridDim.x * blockDim.x;
  for (int i = blockIdx.x * blockDim.x + threadIdx.x; i < n4; i += stride) {
    float4 v = reinterpret_cast<const float4*>(in)[i];
    ushort4 o;
    o.x = f2bfu(v.x); o.y = f2bfu(v.y); o.z = f2bfu(v.z); o.w = f2bfu(v.w);
    reinterpret_cast<ushort4*>(out)[i] = o;
  }
}

// in: f32 [R][Cc] row-major -> out: bf16 [Cc][R]
__global__ __launch_bounds__(256) void transpose_cast(const float* __restrict__ in,
                                                      unsigned short* __restrict__ out,
                                                      int R, int Cc) {
  __shared__ float tile[32][33];
  const int tx = threadIdx.x, ty = threadIdx.y;  // 32 x 8
  const int c0 = blockIdx.x * 32, r0 = blockIdx.y * 32;
  #pragma unroll
  for (int dy = 0; dy < 32; dy += 8)
    tile[ty + dy][tx] = in[(size_t)(r0 + ty + dy) * Cc + (c0 + tx)];
  __syncthreads();
  #pragma unroll
  for (int dy = 0; dy < 32; dy += 8)
    out[(size_t)(c0 + ty + dy) * R + (r0 + tx)] = f2bfu(tile[tx][ty + dy]);
}

// --- 256x128 tile, 8 waves x (64x64), BK=32, 3-ring 72KB, stage-ahead depth 2 ---
// Pipeline: at tile t, read buf[t%3], stage tile t+2 into buf[(t+2)%3] (3 gloads/wave),
// then MFMA; before crossing into tile t+1: s_waitcnt vmcnt(3) retires batch t+1
// (t+2's 3 loads stay in flight) -> issue-to-wait distance ~1.5 tiles >> HBM latency.
// Hazard ledger: buf[(t+2)%3] == buf[(t-1)%3]; its last reads fed MFMAs before
// barrier(t-1), which all waves passed before any stage at tile t. Reads of
// buf[t%3] follow barrier(t-1) whose vmcnt(3) retired batch t.
// LDS layout per buffer (24 KB): A 256x32 packed [128 prow][8 slots 16B],
// prow=m&127, slin=(m>>7)*4+(k>>3), slot s=slin^(prow&7); B 128x32 likewise
// [64 prow][8 slots], prow=n&63.  Staging slot L = tid; dest = buf + wave*1024
// (global_load_lds = wave-uniform base + lane*16); source from slin=s^(prow&7).
// MODE 0: QKV. Q/K blocks (n0<1024): 2-pass LDS-transpose epilogue -> qkT.
//         V blocks: direct vb[bh][n][d] stores.
// MODE 1: proj -> f32 out + bias, row-major.
template <int MODE>
__global__ __launch_bounds__(512, 4) void gemm256(const unsigned short* __restrict__ A,
                                                  const unsigned short* __restrict__ Bt,
                                                  void* __restrict__ out0,
                                                  void* __restrict__ out1,
                                                  const float* __restrict__ bias,
                                                  int M, int Nn, int Kk, int nbx) {
  __shared__ __align__(16) char lds[73728];
  const int nwg = gridDim.x;
  int wg = blockIdx.x;
  wg = (wg & 7) * (nwg >> 3) + (wg >> 3);  // XCD swizzle (nwg % 8 == 0)
  const int bx = wg % nbx, by = wg / nbx;
  const int m0 = by * 256, n0 = bx * 128;

  const int tid = threadIdx.x, wave = tid >> 6, lane = tid & 63;
  const int wr = wave >> 1, wc = wave & 1;
  const int l15 = lane & 15, lg = lane >> 4;
  const int T = Kk >> 5;

  f32x4 acc[4][4] = {};  // 64 regs: wave tile 64 tokens x 64 cols
  short8 af[4], bf[4];

  // staging thread->slot precompute (slot L = tid)
  const int prowA = tid >> 3, sA = tid & 7;
  const int slinA = sA ^ (prowA & 7);
  const int mA = ((slinA >> 2) << 7) + prowA, kA = (slinA & 3) << 3;
  const int prow2 = prowA + 64;                 // second A half: L2 = tid + 512
  const int slin2 = sA ^ (prow2 & 7);
  const int m2 = ((slin2 >> 2) << 7) + prow2, k2 = (slin2 & 3) << 3;
  const int prowB = tid >> 3, sB = tid & 7;
  const int slinB = sB ^ (prowB & 7);
  const int nB = ((slinB >> 2) << 6) + prowB, kB = (slinB & 3) << 3;
  const int woff = wave * 1024;                 // per-wave LDS dest offset

  auto stageAB = [&](int kt, char* buf) {
    gload_lds16(A + (size_t)(m0 + mA) * Kk + kt + kA, buf + woff);
    gload_lds16(A + (size_t)(m0 + m2) * Kk + kt + k2, buf + 8192 + woff);
    gload_lds16(Bt + (size_t)(n0 + nB) * Kk + kt + kB, buf + 16384 + woff);
  };

  auto dsA = [&](const char* bufc) {
    #pragma unroll
    for (int fr = 0; fr < 4; ++fr) {
      const int m = wr * 64 + fr * 16 + l15;
      const int prow = m & 127;
      const int s = ((m >> 7) * 4 + lg) ^ (l15 & 7);
      af[fr] = *reinterpret_cast<const short8*>(bufc + prow * 128 + (s << 4));
    }
  };
  auto dsB = [&](const char* bufc) {
    #pragma unroll
    for (int fc = 0; fc < 4; ++fc) {
      const int prow = fc * 16 + l15;   // n&63
      const int s = (wc * 4 + lg) ^ (l15 & 7);
      bf[fc] = *reinterpret_cast<const short8*>(bufc + 16384 + prow * 128 + (s << 4));
    }
  };

  // prologue: stage tiles 0 and 1
  stageAB(0, lds);
  stageAB(32, lds + 24576);
  asm volatile("s_waitcnt vmcnt(3)" ::: "memory");  // tile 0 landed, tile 1 in flight
  __builtin_amdgcn_s_barrier();

  char* p0 = lds;            // buf for tile t
  char* p1 = lds + 24576;    // buf for tile t+1
  char* p2 = lds + 49152;    // buf for tile t+2 (stage target)

  for (int t = 0; t < T; ++t) {
    dsA(p0);
    dsB(p0);
    const bool st2 = (t + 2 < T);
    if (st2) stageAB((t + 2) << 5, p2);
    __builtin_amdgcn_s_setprio(1);
    #pragma unroll
    for (int fr = 0; fr < 4; ++fr)
      #pragma unroll
      for (int fc = 0; fc < 4; ++fc)
        acc[fr][fc] = __builtin_amdgcn_mfma_f32_16x16x32_bf16(
            af[fr], bf[fc], acc[fr][fc], 0, 0, 0);
    __builtin_amdgcn_s_setprio(0);
    if (t + 1 < T) {
      if (st2) asm volatile("s_waitcnt vmcnt(3)" ::: "memory");
      else     asm volatile("s_waitcnt vmcnt(0)" ::: "memory");
      __builtin_amdgcn_s_barrier();
    }
    char* tmp = p0; p0 = p1; p1 = p2; p2 = tmp;
  }

  // ---------------- epilogue ----------------
  if (MODE == 1) {
    #pragma unroll
    for (int fr = 0; fr < 4; ++fr)
      #pragma unroll
      for (int fc = 0; fc < 4; ++fc) {
        const int row0 = m0 + wr * 64 + fr * 16 + lg * 4;
        const int col = n0 + wc * 64 + fc * 16 + l15;
        #pragma unroll
        for (int v = 0; v < 4; ++v)
          reinterpret_cast<float*>(out0)[(size_t)(row0 + v) * Nn + col] =
              acc[fr][fc][v] + bias[col];
      }
  } else if (n0 < 1024) {
    // Q/K: two 32-KB LDS-transpose passes (wc halves) -> coalesced qkT stores.
    #pragma unroll
    for (int p = 0; p < 2; ++p) {
      __builtin_amdgcn_s_barrier();
      if (wc == p) {
        #pragma unroll
        for (int fr = 0; fr < 4; ++fr)
          #pragma unroll
          for (int fc = 0; fc < 4; ++fc) {
            const int tok = wr * 64 + fr * 16 + lg * 4;  // token-local, %4==0
            const int cl = fc * 16 + l15;                // col within 64-half
            ushort4 o;
            o.x = f2bfu(acc[fr][fc][0]);
            o.y = f2bfu(acc[fr][fc][1]);
            o.z = f2bfu(acc[fr][fc][2]);
            o.w = f2bfu(acc[fr][fc][3]);
            const int byte = cl * 512 + ((tok * 2) ^ ((cl & 7) << 4));
            *reinterpret_cast<ushort4*>(lds + byte) = o;
          }
      }
      __builtin_amdgcn_s_barrier();
      #pragma unroll
      for (int it = 0; it < 4; ++it) {
        const int cl = it * 16 + (tid >> 5);
        const int ns = (tid & 31) * 8;
        const int byte = cl * 512 + ((ns * 2) ^ ((cl & 7) << 4));
        short8 val = *reinterpret_cast<const short8*>(lds + byte);
        const int gcol = n0 + p * 64 + cl;
        const int sel = gcol >> 9, rem = gcol & 511;
        const int bh = (m0 >> 12) * 8 + (rem >> 6), cc = rem & 63;
        *reinterpret_cast<short8*>(&reinterpret_cast<unsigned short*>(out0)[
            ((size_t)sel * 4096 + bh * 64 + cc) * 4096 + (m0 & 4095) + ns]) = val;
      }
    }
  } else {
    // V block: direct vb[bh][n][d] stores
    #pragma unroll
    for (int fr = 0; fr < 4; ++fr)
      #pragma unroll
      for (int fc = 0; fc < 4; ++fc) {
        const int row0 = m0 + wr * 64 + fr * 16 + lg * 4;
        const int col = n0 + wc * 64 + fc * 16 + l15;
        const int rem = col & 511, hh = rem >> 6, cc = rem & 63;
        const int bb = row0 >> 12, nseq = row0 & 4095;
        const int bh = bb * 8 + hh;
        #pragma unroll
        for (int v = 0; v < 4; ++v)
          reinterpret_cast<unsigned short*>(out1)[
              ((size_t)bh * 4096 + nseq + v) * 64 + cc] =
              f2bfu(acc[fr][fc][v]);
      }
  }
}

// ---------------- attn QK^T via MFMA: rawp[s][bh][c][d] partials + norms ----------------
// qkT: [sel][bh][c][n] bf16 (sel 0=Q,1=K), rows of 4096.
__global__ __launch_bounds__(256) void attn_qk(const unsigned short* __restrict__ qkT,
                                               float* __restrict__ rawp,
                                               float* __restrict__ normp) {
  const int bh = blockIdx.x, s = blockIdx.y;
  const int tid = threadIdx.x, w = tid >> 6, lane = tid & 63;
  const int l15 = lane & 15, lg = lane >> 4;
  const int nbase = s * 512 + w * 128;
  const unsigned short* qrow = qkT + (size_t)(bh * 64) * 4096;
  const unsigned short* krow = qkT + (size_t)(4096 + bh * 64) * 4096;

  __shared__ float red[4][64][64];
  __shared__ float nrm[4][2][64];

  f32x4 acc[4][4] = {};
  float sq[4] = {0.f, 0.f, 0.f, 0.f}, sk[4] = {0.f, 0.f, 0.f, 0.f};

  #pragma unroll
  for (int kc = 0; kc < 2; ++kc) {
    short8 aq[4][2], bk[4][2];
    #pragma unroll
    for (int fr = 0; fr < 4; ++fr)
      #pragma unroll
      for (int ks = 0; ks < 2; ++ks) {
        const size_t off = (size_t)(fr * 16 + l15) * 4096 + nbase + (kc * 2 + ks) * 32 + lg * 8;
        aq[fr][ks] = *reinterpret_cast<const short8*>(&qrow[off]);
        bk[fr][ks] = *reinterpret_cast<const short8*>(&krow[off]);
      }
    #pragma unroll
    for (int ks = 0; ks < 2; ++ks)
      #pragma unroll
      for (int fr = 0; fr < 4; ++fr)
        #pragma unroll
        for (int fc = 0; fc < 4; ++fc)
          acc[fr][fc] = __builtin_amdgcn_mfma_f32_16x16x32_bf16(
              aq[fr][ks], bk[fc][ks], acc[fr][fc], 0, 0, 0);
    #pragma unroll
    for (int fr = 0; fr < 4; ++fr)
      #pragma unroll
      for (int ks = 0; ks < 2; ++ks)
        #pragma unroll
        for (int j = 0; j < 8; ++j) {
          const float fq = bfu2f((unsigned short)aq[fr][ks][j]);
          const float fk = bfu2f((unsigned short)bk[fr][ks][j]);
          sq[fr] = fmaf(fq, fq, sq[fr]);
          sk[fr] = fmaf(fk, fk, sk[fr]);
        }
  }

  #pragma unroll
  for (int fr = 0; fr < 4; ++fr) {
    sq[fr] += __shfl_xor(sq[fr], 16); sq[fr] += __shfl_xor(sq[fr], 32);
    sk[fr] += __shfl_xor(sk[fr], 16); sk[fr] += __shfl_xor(sk[fr], 32);
  }
  if (lane < 16) {
    #pragma unroll
    for (int fr = 0; fr < 4; ++fr) {
      nrm[w][0][fr * 16 + lane] = sq[fr];
      nrm[w][1][fr * 16 + lane] = sk[fr];
    }
  }
  #pragma unroll
  for (int fr = 0; fr < 4; ++fr)
    #pragma unroll
    for (int fc = 0; fc < 4; ++fc)
      #pragma unroll
      for (int v = 0; v < 4; ++v)
        red[w][fr * 16 + lg * 4 + v][fc * 16 + l15] = acc[fr][fc][v];
  __syncthreads();

  const float* rf = &red[0][0][0];
  float* rp = rawp + ((size_t)s * 64 + bh) * 4096;
  for (int i = tid; i < 4096; i += 256)
    rp[i] = rf[i] + rf[4096 + i] + rf[8192 + i] + rf[12288 + i];
  const float* nf = &nrm[0][0][0];
  if (tid < 128) {
    float* np = normp + ((size_t)s * 64 + bh) * 128;
    np[tid] = nf[tid] + nf[128 + tid] + nf[256 + tid] + nf[384 + tid];
  }
}

// ---------------- finalize: reduce partials, normalize, softmax ----------------
__global__ __launch_bounds__(64) void attn_finalize(const float* __restrict__ rawp,
                                                    const float* __restrict__ normp,
                                                    const float* __restrict__ temperature,
                                                    unsigned short* __restrict__ attnP) {
  const int bh = blockIdx.x, c8 = blockIdx.y, h = bh & 7;
  const int d = threadIdx.x;
  float nq = 0.f, nk = 0.f;
  for (int s = 0; s < NSPL; ++s) {
    nq += normp[((size_t)s * 64 + bh) * 128 + d];
    nk += normp[((size_t)s * 64 + bh) * 128 + 64 + d];
  }
  nq = fmaxf(sqrtf(nq), 1e-12f);
  nk = fmaxf(sqrtf(nk), 1e-12f);
  const float t = temperature[h];
  for (int i = 0; i < 8; ++i) {
    const int c = c8 * 8 + i;
    float r = 0.f;
    for (int s = 0; s < NSPL; ++s)
      r += rawp[((size_t)s * 64 + bh) * 4096 + c * 64 + d];
    const float nqc = __shfl(nq, c);
    float v = r * t / (nqc * nk);
    float m = v;
    #pragma unroll
    for (int off = 32; off > 0; off >>= 1) m = fmaxf(m, __shfl_xor(m, off));
    float e = __expf(v - m);
    float ssum = e;
    #pragma unroll
    for (int off = 32; off > 0; off >>= 1) ssum += __shfl_xor(ssum, off);
    attnP[(size_t)bh * 4096 + c * 64 + d] = f2bfu(e / ssum);
  }
}

// ---------------- PV via MFMA: y[b*4096+n][h*64+c] = sum_d P[c,d] * vb[bh][n][d] --------
__global__ __launch_bounds__(256) void pv_mfma(const unsigned short* __restrict__ attnP,
                                               const unsigned short* __restrict__ vb,
                                               unsigned short* __restrict__ y) {
  const int nc = blockIdx.x, bh = blockIdx.y;
  const int b = bh >> 3, h = bh & 7;
  const int tid = threadIdx.x, w = tid >> 6, lane = tid & 63;
  const int l15 = lane & 15, lg = lane >> 4;
  const int n0 = nc * 256 + w * 64;

  short8 ap[4][2], bv[4][2];
  #pragma unroll
  for (int fr = 0; fr < 4; ++fr)
    #pragma unroll
    for (int ks = 0; ks < 2; ++ks)
      ap[fr][ks] = *reinterpret_cast<const short8*>(
          &attnP[(size_t)bh * 4096 + (fr * 16 + l15) * 64 + ks * 32 + lg * 8]);
  #pragma unroll
  for (int fc = 0; fc < 4; ++fc)
    #pragma unroll
    for (int ks = 0; ks < 2; ++ks)
      bv[fc][ks] = *reinterpret_cast<const short8*>(
          &vb[((size_t)bh * 4096 + n0 + fc * 16 + l15) * 64 + ks * 32 + lg * 8]);

  f32x4 acc[4][4] = {};
  #pragma unroll
  for (int ks = 0; ks < 2; ++ks)
    #pragma unroll
    for (int fr = 0; fr < 4; ++fr)
      #pragma unroll
      for (int fc = 0; fc < 4; ++fc)
        acc[fr][fc] = __builtin_amdgcn_mfma_f32_16x16x32_bf16(
            ap[fr][ks], bv[fc][ks], acc[fr][fc], 0, 0, 0);

  #pragma unroll
  for (int fr = 0; fr < 4; ++fr)
    #pragma unroll
    for (int fc = 0; fc < 4; ++fc) {
      const int n = n0 + fc * 16 + l15;
      const int c0 = fr * 16 + lg * 4;
      ushort4 o;
      o.x = f2bfu(acc[fr][fc][0]); o.y = f2bfu(acc[fr][fc][1]);
      o.z = f2bfu(acc[fr][fc][2]); o.w = f2bfu(acc[fr][fc][3]);
      *reinterpret_cast<ushort4*>(
          &y[((size_t)b * 4096 + n) * 512 + h * 64 + c0]) = o;
    }
}

extern "C" void kernel_launch(void* const* d_in, const int* in_sizes, int n_in,
                              void* d_out, int out_size, void* d_ws, size_t ws_size,
                              hipStream_t stream) {
  const float* x = (const float*)d_in[0];
  const float* Wqkv = (const float*)d_in[2];
  const float* temp = (const float*)d_in[3];
  const float* Wproj = (const float*)d_in[4];
  const float* bproj = (const float*)d_in[5];
  float* out = (float*)d_out;

  char* w = (char*)d_ws;
  unsigned short* xb = (unsigned short*)w;    w += (size_t)MTOK * CH * 2;
  unsigned short* wqT = (unsigned short*)w;   w += (size_t)K3C * CH * 2;
  unsigned short* wpT = (unsigned short*)w;   w += (size_t)CH * CH * 2;
  unsigned short* qkT = (unsigned short*)w;   w += (size_t)2 * 64 * 64 * 4096 * 2;
  unsigned short* vb = (unsigned short*)w;    w += (size_t)64 * 4096 * 64 * 2;
  unsigned short* yb = (unsigned short*)w;    w += (size_t)MTOK * CH * 2;
  float* rawp = (float*)w;                    w += (size_t)NSPL * 64 * 4096 * 4;
  float* normp = (float*)w;                   w += (size_t)NSPL * 64 * 128 * 4;
  unsigned short* attnP = (unsigned short*)w; w += (size_t)64 * 4096 * 2;

  cast_f32_bf16<<<2048, 256, 0, stream>>>(x, xb, MTOK * CH / 4);
  transpose_cast<<<dim3(K3C / 32, CH / 32), dim3(32, 8), 0, stream>>>(Wqkv, wqT, CH, K3C);
  transpose_cast<<<dim3(CH / 32, CH / 32), dim3(32, 8), 0, stream>>>(Wproj, wpT, CH, CH);
  gemm256<0><<<1536, 512, 0, stream>>>(xb, wqT, qkT, vb, nullptr, MTOK, K3C, CH, 12);
  attn_qk<<<dim3(64, 8), 256, 0, stream>>>(qkT, rawp, normp);
  attn_finalize<<<dim3(64, 8), 64, 0, stream>>>(rawp, normp, temp, attnP);
  pv_mfma<<<dim3(16, 64), 256, 0, stream>>>(attnP, vb, yb);
  gemm256<1><<<512, 512, 0, stream>>>(yb, wpT, out, nullptr, bproj, MTOK, CH, CH, 4);
}